// Round 1
// baseline (735.658 us; speedup 1.0000x reference)
//
#include <hip/hip_runtime.h>

#define D 64  // D_IN == D_OUT == 64

__device__ __forceinline__ void fma4(float4& c, float a, const float4& b) {
  c.x = fmaf(a, b.x, c.x);
  c.y = fmaf(a, b.y, c.y);
  c.z = fmaf(a, b.z, c.z);
  c.w = fmaf(a, b.w, c.w);
}

// Compute outp[n][:] = feat[n][:] @ W for a 128-node tile.
// Block = 256 threads. LDS: W (64x64) + featT (64 x 132 padded) ~= 50 KB.
// Each thread: 8 rows x 4 cols register tile.
__device__ void proj_tile(const float* __restrict__ feat, const float* __restrict__ W,
                          float* __restrict__ outp, int N, int tileBase) {
  __shared__ float sW[64 * 64];
  __shared__ float sF[64 * 132];
  const int t = threadIdx.x;

  // Stage W (4096 floats) via float4.
  {
    const float4* Wv = (const float4*)W;
    float4* sWv = (float4*)sW;
    for (int k = t; k < 1024; k += 256) sWv[k] = Wv[k];
  }
  // Stage feat tile transposed: sF[i][node_local], 2 threads per row.
  {
    const int row = t >> 1, half = t & 1;
    const int gr = tileBase + row;
    if (gr < N) {
      const float4* src = (const float4*)(feat + (size_t)gr * D + half * 32);
#pragma unroll
      for (int k = 0; k < 8; ++k) {
        float4 v = src[k];
        int i0 = half * 32 + k * 4;
        sF[(i0 + 0) * 132 + row] = v.x;
        sF[(i0 + 1) * 132 + row] = v.y;
        sF[(i0 + 2) * 132 + row] = v.z;
        sF[(i0 + 3) * 132 + row] = v.w;
      }
    } else {
#pragma unroll
      for (int k = 0; k < 8; ++k) {
        int i0 = half * 32 + k * 4;
        sF[(i0 + 0) * 132 + row] = 0.f;
        sF[(i0 + 1) * 132 + row] = 0.f;
        sF[(i0 + 2) * 132 + row] = 0.f;
        sF[(i0 + 3) * 132 + row] = 0.f;
      }
    }
  }
  __syncthreads();

  const int c0 = (t & 15) * 4;   // output col group
  const int r0 = (t >> 4) * 8;   // local row group
  float4 acc[8];
#pragma unroll
  for (int rr = 0; rr < 8; ++rr) acc[rr] = make_float4(0.f, 0.f, 0.f, 0.f);

#pragma unroll 8
  for (int i = 0; i < 64; ++i) {
    float4 w  = *(const float4*)&sW[i * 64 + c0];
    float4 a0 = *(const float4*)&sF[i * 132 + r0];
    float4 a1 = *(const float4*)&sF[i * 132 + r0 + 4];
    fma4(acc[0], a0.x, w); fma4(acc[1], a0.y, w);
    fma4(acc[2], a0.z, w); fma4(acc[3], a0.w, w);
    fma4(acc[4], a1.x, w); fma4(acc[5], a1.y, w);
    fma4(acc[6], a1.z, w); fma4(acc[7], a1.w, w);
  }

#pragma unroll
  for (int rr = 0; rr < 8; ++rr) {
    int gn = tileBase + r0 + rr;
    if (gn < N) *(float4*)(outp + (size_t)gn * D + c0) = acc[rr];
  }
}

// Fast path: y = 0..R-1 -> proj[y]; y = R -> self-loop into out.
__global__ __launch_bounds__(256, 3) void proj_all(const float* __restrict__ feat,
                                                   const float* __restrict__ weight,
                                                   const float* __restrict__ loopw,
                                                   float* __restrict__ proj,
                                                   float* __restrict__ out, int N, int R) {
  const int m = blockIdx.y;
  const float* W = (m < R) ? weight + (size_t)m * D * D : loopw;
  float* o = (m < R) ? proj + (size_t)m * N * D : out;
  proj_tile(feat, W, o, N, blockIdx.x * 128);
}

// Fallback path: single matrix.
__global__ __launch_bounds__(256, 3) void proj_single(const float* __restrict__ feat,
                                                      const float* __restrict__ W,
                                                      float* __restrict__ o, int N) {
  proj_tile(feat, W, o, N, blockIdx.x * 128);
}

// 4 edges per wave; 16 lanes x float4 per edge. Coalesced 256B proj read per edge.
__global__ __launch_bounds__(256, 8) void edge_scatter(const int* __restrict__ esrc,
                                                       const int* __restrict__ edst,
                                                       const int* __restrict__ etype,
                                                       const float* __restrict__ att,
                                                       const float* __restrict__ proj,
                                                       const float* __restrict__ hbias,
                                                       float* __restrict__ out,
                                                       int E, int N, int relFilter) {
  const int t = blockIdx.x * 256 + threadIdx.x;
  const int wave = t >> 6;
  const int lane = threadIdx.x & 63;
  const int sub = lane >> 4;
  const int q = lane & 15;
  const long e = (long)wave * 4 + sub;
  if (e >= E) return;
  const int r = etype[e];
  if (relFilter >= 0 && r != relFilter) return;
  const int s = esrc[e];
  const int dn = edst[e];
  const float a = att[e];
  const size_t base = (relFilter >= 0) ? (size_t)s * D : ((size_t)r * N + s) * D;
  const float4 hb = ((const float4*)hbias)[q];
  const float4 p = *(const float4*)(proj + base + q * 4);
  float* op = out + (size_t)dn * D + q * 4;
  unsafeAtomicAdd(op + 0, (p.x + hb.x) * a);
  unsafeAtomicAdd(op + 1, (p.y + hb.y) * a);
  unsafeAtomicAdd(op + 2, (p.z + hb.z) * a);
  unsafeAtomicAdd(op + 3, (p.w + hb.w) * a);
}

extern "C" void kernel_launch(void* const* d_in, const int* in_sizes, int n_in,
                              void* d_out, int out_size, void* d_ws, size_t ws_size,
                              hipStream_t stream) {
  const float* feat  = (const float*)d_in[0];
  const int* esrc    = (const int*)d_in[1];
  const int* edst    = (const int*)d_in[2];
  const int* etype   = (const int*)d_in[3];
  const float* att   = (const float*)d_in[4];
  const float* weight= (const float*)d_in[5];
  const float* hbias = (const float*)d_in[6];
  const float* loopw = (const float*)d_in[7];
  float* out = (float*)d_out;

  const int N = in_sizes[0] / D;          // 50000
  const int E = in_sizes[1];              // 800000
  const int R = in_sizes[5] / (D * D);    // 8

  float* proj = (float*)d_ws;
  const size_t need = (size_t)R * N * D * sizeof(float);

  const int tilesN = (N + 127) / 128;
  const int eblocks = (E + 15) / 16;

  if (ws_size >= need) {
    proj_all<<<dim3(tilesN, R + 1), 256, 0, stream>>>(feat, weight, loopw, proj, out, N, R);
    edge_scatter<<<eblocks, 256, 0, stream>>>(esrc, edst, etype, att, proj, hbias, out, E, N, -1);
  } else {
    // Per-relation fallback: needs only N*D floats of scratch.
    proj_single<<<tilesN, 256, 0, stream>>>(feat, loopw, out, N);
    for (int r = 0; r < R; ++r) {
      proj_single<<<tilesN, 256, 0, stream>>>(feat, weight + (size_t)r * D * D, proj, N);
      edge_scatter<<<eblocks, 256, 0, stream>>>(esrc, edst, etype, att, proj, hbias, out, E, N, r);
    }
  }
}

// Round 2
// 282.076 us; speedup vs baseline: 2.6080x; 2.6080x over previous
//
#include <hip/hip_runtime.h>

#define D 64  // D_IN == D_OUT == 64

__device__ __forceinline__ void fma4(float4& c, float a, const float4& b) {
  c.x = fmaf(a, b.x, c.x);
  c.y = fmaf(a, b.y, c.y);
  c.z = fmaf(a, b.z, c.z);
  c.w = fmaf(a, b.w, c.w);
}

// ---------------- projection GEMM (unchanged from R1, correct) ----------------
__device__ void proj_tile(const float* __restrict__ feat, const float* __restrict__ W,
                          float* __restrict__ outp, int N, int tileBase) {
  __shared__ float sW[64 * 64];
  __shared__ float sF[64 * 132];
  const int t = threadIdx.x;

  {
    const float4* Wv = (const float4*)W;
    float4* sWv = (float4*)sW;
    for (int k = t; k < 1024; k += 256) sWv[k] = Wv[k];
  }
  {
    const int row = t >> 1, half = t & 1;
    const int gr = tileBase + row;
    if (gr < N) {
      const float4* src = (const float4*)(feat + (size_t)gr * D + half * 32);
#pragma unroll
      for (int k = 0; k < 8; ++k) {
        float4 v = src[k];
        int i0 = half * 32 + k * 4;
        sF[(i0 + 0) * 132 + row] = v.x;
        sF[(i0 + 1) * 132 + row] = v.y;
        sF[(i0 + 2) * 132 + row] = v.z;
        sF[(i0 + 3) * 132 + row] = v.w;
      }
    } else {
#pragma unroll
      for (int k = 0; k < 8; ++k) {
        int i0 = half * 32 + k * 4;
        sF[(i0 + 0) * 132 + row] = 0.f;
        sF[(i0 + 1) * 132 + row] = 0.f;
        sF[(i0 + 2) * 132 + row] = 0.f;
        sF[(i0 + 3) * 132 + row] = 0.f;
      }
    }
  }
  __syncthreads();

  const int c0 = (t & 15) * 4;
  const int r0 = (t >> 4) * 8;
  float4 acc[8];
#pragma unroll
  for (int rr = 0; rr < 8; ++rr) acc[rr] = make_float4(0.f, 0.f, 0.f, 0.f);

#pragma unroll 8
  for (int i = 0; i < 64; ++i) {
    float4 w  = *(const float4*)&sW[i * 64 + c0];
    float4 a0 = *(const float4*)&sF[i * 132 + r0];
    float4 a1 = *(const float4*)&sF[i * 132 + r0 + 4];
    fma4(acc[0], a0.x, w); fma4(acc[1], a0.y, w);
    fma4(acc[2], a0.z, w); fma4(acc[3], a0.w, w);
    fma4(acc[4], a1.x, w); fma4(acc[5], a1.y, w);
    fma4(acc[6], a1.z, w); fma4(acc[7], a1.w, w);
  }

#pragma unroll
  for (int rr = 0; rr < 8; ++rr) {
    int gn = tileBase + r0 + rr;
    if (gn < N) *(float4*)(outp + (size_t)gn * D + c0) = acc[rr];
  }
}

__global__ __launch_bounds__(256, 3) void proj_all(const float* __restrict__ feat,
                                                   const float* __restrict__ weight,
                                                   const float* __restrict__ loopw,
                                                   float* __restrict__ proj,
                                                   float* __restrict__ out, int N, int R) {
  const int m = blockIdx.y;
  const float* W = (m < R) ? weight + (size_t)m * D * D : loopw;
  float* o = (m < R) ? proj + (size_t)m * N * D : out;
  proj_tile(feat, W, o, N, blockIdx.x * 128);
}

__global__ __launch_bounds__(256, 3) void proj_single(const float* __restrict__ feat,
                                                      const float* __restrict__ W,
                                                      float* __restrict__ o, int N) {
  proj_tile(feat, W, o, N, blockIdx.x * 128);
}

// ---------------- CSR build ----------------
__global__ void zero_ints(int* __restrict__ p, int n) {
  int i = blockIdx.x * 256 + threadIdx.x;
  if (i < n) p[i] = 0;
}

__global__ void hist_dst(const int* __restrict__ edst, int* __restrict__ deg, int E) {
  int e = blockIdx.x * 256 + threadIdx.x;
  if (e < E) atomicAdd(&deg[edst[e]], 1);
}

// Single-block exclusive scan over N counts -> off[N+1], cursor[N].
__global__ __launch_bounds__(1024) void scan_deg(const int* __restrict__ deg,
                                                 int* __restrict__ off,
                                                 int* __restrict__ cursor, int N) {
  __shared__ int s[1024];
  __shared__ int carry;
  if (threadIdx.x == 0) carry = 0;
  __syncthreads();
  for (int base = 0; base < N; base += 1024) {
    int i = base + (int)threadIdx.x;
    int v = (i < N) ? deg[i] : 0;
    s[threadIdx.x] = v;
    __syncthreads();
#pragma unroll
    for (int d = 1; d < 1024; d <<= 1) {
      int t = (threadIdx.x >= (unsigned)d) ? s[threadIdx.x - d] : 0;
      __syncthreads();
      s[threadIdx.x] += t;
      __syncthreads();
    }
    int exc = s[threadIdx.x] - v + carry;   // reads carry before update below
    if (i < N) { off[i] = exc; cursor[i] = exc; }
    __syncthreads();
    if (threadIdx.x == 1023) carry += s[1023];
    __syncthreads();
  }
  if (threadIdx.x == 0) off[N] = carry;
}

// Scatter edge payloads into dst-sorted order.
__global__ void scatter_idx(const int* __restrict__ esrc, const int* __restrict__ edst,
                            const int* __restrict__ etype, const float* __restrict__ att,
                            int* __restrict__ cursor, int* __restrict__ ssr,
                            float* __restrict__ satt, int E) {
  int e = blockIdx.x * 256 + threadIdx.x;
  if (e >= E) return;
  int d = edst[e];
  int pos = atomicAdd(&cursor[d], 1);
  ssr[pos] = esrc[e] | (etype[e] << 24);
  satt[pos] = att[e];
}

// One node per 64-lane wave: 4 edge-subgroups x 16 lanes x float4.
__global__ __launch_bounds__(256, 8) void node_gather(const int* __restrict__ off,
                                                      const int* __restrict__ ssr,
                                                      const float* __restrict__ satt,
                                                      const float* __restrict__ proj,
                                                      const float* __restrict__ hbias,
                                                      float* __restrict__ out, int N) {
  const int n = (blockIdx.x * 256 + threadIdx.x) >> 6;
  if (n >= N) return;
  const int lane = threadIdx.x & 63;
  const int sub = lane >> 4;
  const int q = lane & 15;

  const int s0 = off[n], s1 = off[n + 1];
  float4 acc = make_float4(0.f, 0.f, 0.f, 0.f);
  float sa = 0.f;
  for (int e = s0 + sub; e < s1; e += 4) {
    const int sr = ssr[e];
    const float a = satt[e];
    const int src = sr & 0x00FFFFFF;
    const int r = ((unsigned)sr) >> 24;
    const float4 p = *(const float4*)(proj + ((size_t)r * N + src) * D + q * 4);
    acc.x = fmaf(a, p.x, acc.x);
    acc.y = fmaf(a, p.y, acc.y);
    acc.z = fmaf(a, p.z, acc.z);
    acc.w = fmaf(a, p.w, acc.w);
    sa += a;
  }
#pragma unroll
  for (int m = 16; m < 64; m <<= 1) {
    acc.x += __shfl_xor(acc.x, m);
    acc.y += __shfl_xor(acc.y, m);
    acc.z += __shfl_xor(acc.z, m);
    acc.w += __shfl_xor(acc.w, m);
    sa += __shfl_xor(sa, m);
  }
  if (sub == 0) {
    const float4 hb = ((const float4*)hbias)[q];
    float* op = out + (size_t)n * D + q * 4;
    float4 cur = *(float4*)op;      // self-loop already there
    cur.x += acc.x + sa * hb.x;
    cur.y += acc.y + sa * hb.y;
    cur.z += acc.z + sa * hb.z;
    cur.w += acc.w + sa * hb.w;
    *(float4*)op = cur;
  }
}

// ---------------- fallback: atomic scatter (R1 version) ----------------
__global__ __launch_bounds__(256, 8) void edge_scatter(const int* __restrict__ esrc,
                                                       const int* __restrict__ edst,
                                                       const int* __restrict__ etype,
                                                       const float* __restrict__ att,
                                                       const float* __restrict__ proj,
                                                       const float* __restrict__ hbias,
                                                       float* __restrict__ out,
                                                       int E, int N, int relFilter) {
  const int t = blockIdx.x * 256 + threadIdx.x;
  const int wave = t >> 6;
  const int lane = threadIdx.x & 63;
  const int sub = lane >> 4;
  const int q = lane & 15;
  const long e = (long)wave * 4 + sub;
  if (e >= E) return;
  const int r = etype[e];
  if (relFilter >= 0 && r != relFilter) return;
  const int s = esrc[e];
  const int dn = edst[e];
  const float a = att[e];
  const size_t base = (relFilter >= 0) ? (size_t)s * D : ((size_t)r * N + s) * D;
  const float4 hb = ((const float4*)hbias)[q];
  const float4 p = *(const float4*)(proj + base + q * 4);
  float* op = out + (size_t)dn * D + q * 4;
  unsafeAtomicAdd(op + 0, (p.x + hb.x) * a);
  unsafeAtomicAdd(op + 1, (p.y + hb.y) * a);
  unsafeAtomicAdd(op + 2, (p.z + hb.z) * a);
  unsafeAtomicAdd(op + 3, (p.w + hb.w) * a);
}

extern "C" void kernel_launch(void* const* d_in, const int* in_sizes, int n_in,
                              void* d_out, int out_size, void* d_ws, size_t ws_size,
                              hipStream_t stream) {
  const float* feat   = (const float*)d_in[0];
  const int* esrc     = (const int*)d_in[1];
  const int* edst     = (const int*)d_in[2];
  const int* etype    = (const int*)d_in[3];
  const float* att    = (const float*)d_in[4];
  const float* weight = (const float*)d_in[5];
  const float* hbias  = (const float*)d_in[6];
  const float* loopw  = (const float*)d_in[7];
  float* out = (float*)d_out;

  const int N = in_sizes[0] / D;          // 50000
  const int E = in_sizes[1];              // 800000
  const int R = in_sizes[5] / (D * D);    // 8

  const size_t projFloats = (size_t)R * N * D;
  const size_t extraInts  = (size_t)(3 * N + 1) + 2 * (size_t)E;  // off,cursor,deg,ssr,satt
  const size_t needSorted = (projFloats + extraInts) * 4;
  const size_t needAtomic = projFloats * 4;

  float* proj = (float*)d_ws;
  const int tilesN = (N + 127) / 128;
  const int eblocks256 = (E + 255) / 256;

  if (ws_size >= needSorted) {
    int* off    = (int*)(proj + projFloats);
    int* cursor = off + (N + 1);
    int* deg    = cursor + N;
    int* ssr    = deg + N;
    float* satt = (float*)(ssr + E);

    proj_all<<<dim3(tilesN, R + 1), 256, 0, stream>>>(feat, weight, loopw, proj, out, N, R);
    zero_ints<<<(N + 255) / 256, 256, 0, stream>>>(deg, N);
    hist_dst<<<eblocks256, 256, 0, stream>>>(edst, deg, E);
    scan_deg<<<1, 1024, 0, stream>>>(deg, off, cursor, N);
    scatter_idx<<<eblocks256, 256, 0, stream>>>(esrc, edst, etype, att, cursor, ssr, satt, E);
    node_gather<<<(N + 3) / 4, 256, 0, stream>>>(off, ssr, satt, proj, hbias, out, N);
  } else if (ws_size >= needAtomic) {
    const int eblocks16 = (E + 15) / 16;
    proj_all<<<dim3(tilesN, R + 1), 256, 0, stream>>>(feat, weight, loopw, proj, out, N, R);
    edge_scatter<<<eblocks16, 256, 0, stream>>>(esrc, edst, etype, att, proj, hbias, out, E, N, -1);
  } else {
    const int eblocks16 = (E + 15) / 16;
    proj_single<<<tilesN, 256, 0, stream>>>(feat, loopw, out, N);
    for (int r = 0; r < R; ++r) {
      proj_single<<<tilesN, 256, 0, stream>>>(feat, weight + (size_t)r * D * D, proj, N);
      edge_scatter<<<eblocks16, 256, 0, stream>>>(esrc, edst, etype, att, proj, hbias, out, E, N, r);
    }
  }
}

// Round 3
// 199.163 us; speedup vs baseline: 3.6938x; 1.4163x over previous
//
#include <hip/hip_runtime.h>

#define D 64  // D_IN == D_OUT == 64

__device__ __forceinline__ void fma4(float4& c, float a, const float4& b) {
  c.x = fmaf(a, b.x, c.x);
  c.y = fmaf(a, b.y, c.y);
  c.z = fmaf(a, b.z, c.z);
  c.w = fmaf(a, b.w, c.w);
}

// ---------------- projection GEMM ----------------
__device__ void proj_tile(const float* __restrict__ feat, const float* __restrict__ W,
                          float* __restrict__ outp, int N, int tileBase) {
  __shared__ float sW[64 * 64];
  __shared__ float sF[64 * 132];
  const int t = threadIdx.x;

  {
    const float4* Wv = (const float4*)W;
    float4* sWv = (float4*)sW;
    for (int k = t; k < 1024; k += 256) sWv[k] = Wv[k];
  }
  {
    const int row = t >> 1, half = t & 1;
    const int gr = tileBase + row;
    if (gr < N) {
      const float4* src = (const float4*)(feat + (size_t)gr * D + half * 32);
#pragma unroll
      for (int k = 0; k < 8; ++k) {
        float4 v = src[k];
        int i0 = half * 32 + k * 4;
        sF[(i0 + 0) * 132 + row] = v.x;
        sF[(i0 + 1) * 132 + row] = v.y;
        sF[(i0 + 2) * 132 + row] = v.z;
        sF[(i0 + 3) * 132 + row] = v.w;
      }
    } else {
#pragma unroll
      for (int k = 0; k < 8; ++k) {
        int i0 = half * 32 + k * 4;
        sF[(i0 + 0) * 132 + row] = 0.f;
        sF[(i0 + 1) * 132 + row] = 0.f;
        sF[(i0 + 2) * 132 + row] = 0.f;
        sF[(i0 + 3) * 132 + row] = 0.f;
      }
    }
  }
  __syncthreads();

  const int c0 = (t & 15) * 4;
  const int r0 = (t >> 4) * 8;
  float4 acc[8];
#pragma unroll
  for (int rr = 0; rr < 8; ++rr) acc[rr] = make_float4(0.f, 0.f, 0.f, 0.f);

#pragma unroll 8
  for (int i = 0; i < 64; ++i) {
    float4 w  = *(const float4*)&sW[i * 64 + c0];
    float4 a0 = *(const float4*)&sF[i * 132 + r0];
    float4 a1 = *(const float4*)&sF[i * 132 + r0 + 4];
    fma4(acc[0], a0.x, w); fma4(acc[1], a0.y, w);
    fma4(acc[2], a0.z, w); fma4(acc[3], a0.w, w);
    fma4(acc[4], a1.x, w); fma4(acc[5], a1.y, w);
    fma4(acc[6], a1.z, w); fma4(acc[7], a1.w, w);
  }

#pragma unroll
  for (int rr = 0; rr < 8; ++rr) {
    int gn = tileBase + r0 + rr;
    if (gn < N) *(float4*)(outp + (size_t)gn * D + c0) = acc[rr];
  }
}

__global__ __launch_bounds__(256, 3) void proj_all(const float* __restrict__ feat,
                                                   const float* __restrict__ weight,
                                                   const float* __restrict__ loopw,
                                                   float* __restrict__ proj,
                                                   float* __restrict__ out, int N, int R) {
  const int m = blockIdx.y;
  const float* W = (m < R) ? weight + (size_t)m * D * D : loopw;
  float* o = (m < R) ? proj + (size_t)m * N * D : out;
  proj_tile(feat, W, o, N, blockIdx.x * 128);
}

__global__ __launch_bounds__(256, 3) void proj_single(const float* __restrict__ feat,
                                                      const float* __restrict__ W,
                                                      float* __restrict__ o, int N) {
  proj_tile(feat, W, o, N, blockIdx.x * 128);
}

// ---------------- CSR build ----------------
__global__ void zero_ints(int* __restrict__ p, int n) {
  int i = blockIdx.x * 256 + threadIdx.x;
  if (i < n) p[i] = 0;
}

__global__ void hist_dst(const int* __restrict__ edst, int* __restrict__ deg, int E) {
  int e = blockIdx.x * 256 + threadIdx.x;
  if (e < E) atomicAdd(&deg[edst[e]], 1);
}

// Two-level scan: (1) per-block sums of 1024 elements.
__global__ __launch_bounds__(256) void scan_partial(const int* __restrict__ deg,
                                                    int* __restrict__ bsum, int N) {
  const int t = threadIdx.x;
  const int base = blockIdx.x * 1024 + t * 4;
  int s = 0;
  if (base + 3 < N) {
    int4 v = *(const int4*)(deg + base);
    s = v.x + v.y + v.z + v.w;
  } else {
#pragma unroll
    for (int k = 0; k < 4; ++k) if (base + k < N) s += deg[base + k];
  }
  __shared__ int red[4];
#pragma unroll
  for (int m = 1; m < 64; m <<= 1) s += __shfl_xor(s, m);
  if ((t & 63) == 0) red[t >> 6] = s;
  __syncthreads();
  if (t == 0) bsum[blockIdx.x] = red[0] + red[1] + red[2] + red[3];
}

// (2) scan block sums (nb can exceed 256 via carry loop), write total to off[N].
__global__ __launch_bounds__(256) void scan_bsum(const int* __restrict__ bsum,
                                                 int* __restrict__ boff,
                                                 int* __restrict__ off, int nb, int N) {
  __shared__ int s[256];
  __shared__ int carry_s;
  const int t = threadIdx.x;
  if (t == 0) carry_s = 0;
  __syncthreads();
  for (int base = 0; base < nb; base += 256) {
    int i = base + t;
    int v = (i < nb) ? bsum[i] : 0;
    s[t] = v;
    __syncthreads();
#pragma unroll
    for (int d = 1; d < 256; d <<= 1) {
      int u = (t >= d) ? s[t - d] : 0;
      __syncthreads();
      s[t] += u;
      __syncthreads();
    }
    int c = carry_s;
    if (i < nb) boff[i] = s[t] - v + c;
    __syncthreads();
    if (t == 0) carry_s = c + s[255];
    __syncthreads();
  }
  if (t == 0) off[N] = carry_s;
}

// (3) re-read degrees, in-block exclusive scan + block offset -> off, cursor.
__global__ __launch_bounds__(256) void scan_apply(const int* __restrict__ deg,
                                                  const int* __restrict__ boff,
                                                  int* __restrict__ off,
                                                  int* __restrict__ cursor, int N) {
  const int t = threadIdx.x;
  const int base = blockIdx.x * 1024 + t * 4;
  int v0 = 0, v1 = 0, v2 = 0, v3 = 0;
  if (base + 3 < N) {
    int4 v = *(const int4*)(deg + base);
    v0 = v.x; v1 = v.y; v2 = v.z; v3 = v.w;
  } else {
    if (base + 0 < N) v0 = deg[base + 0];
    if (base + 1 < N) v1 = deg[base + 1];
    if (base + 2 < N) v2 = deg[base + 2];
  }
  const int tsum = v0 + v1 + v2 + v3;
  __shared__ int s[256];
  s[t] = tsum;
  __syncthreads();
#pragma unroll
  for (int d = 1; d < 256; d <<= 1) {
    int u = (t >= d) ? s[t - d] : 0;
    __syncthreads();
    s[t] += u;
    __syncthreads();
  }
  int exc = s[t] - tsum + boff[blockIdx.x];
  const int o1 = exc + v0, o2 = o1 + v1, o3 = o2 + v2;
  if (base + 0 < N) { off[base + 0] = exc; cursor[base + 0] = exc; }
  if (base + 1 < N) { off[base + 1] = o1;  cursor[base + 1] = o1; }
  if (base + 2 < N) { off[base + 2] = o2;  cursor[base + 2] = o2; }
  if (base + 3 < N) { off[base + 3] = o3;  cursor[base + 3] = o3; }
}

// Scatter edge payloads into dst-sorted order.
__global__ void scatter_idx(const int* __restrict__ esrc, const int* __restrict__ edst,
                            const int* __restrict__ etype, const float* __restrict__ att,
                            int* __restrict__ cursor, int* __restrict__ ssr,
                            float* __restrict__ satt, int E) {
  int e = blockIdx.x * 256 + threadIdx.x;
  if (e >= E) return;
  int d = edst[e];
  int pos = atomicAdd(&cursor[d], 1);
  ssr[pos] = esrc[e] | (etype[e] << 24);
  satt[pos] = att[e];
}

// One node per 64-lane wave: 4 edge-subgroups x 16 lanes x float4.
__global__ __launch_bounds__(256, 8) void node_gather(const int* __restrict__ off,
                                                      const int* __restrict__ ssr,
                                                      const float* __restrict__ satt,
                                                      const float* __restrict__ proj,
                                                      const float* __restrict__ hbias,
                                                      float* __restrict__ out, int N) {
  const int n = (blockIdx.x * 256 + threadIdx.x) >> 6;
  if (n >= N) return;
  const int lane = threadIdx.x & 63;
  const int sub = lane >> 4;
  const int q = lane & 15;

  const int s0 = off[n], s1 = off[n + 1];
  float4 acc = make_float4(0.f, 0.f, 0.f, 0.f);
  float sa = 0.f;
  for (int e = s0 + sub; e < s1; e += 4) {
    const int sr = ssr[e];
    const float a = satt[e];
    const int src = sr & 0x00FFFFFF;
    const int r = ((unsigned)sr) >> 24;
    const float4 p = *(const float4*)(proj + ((size_t)r * N + src) * D + q * 4);
    acc.x = fmaf(a, p.x, acc.x);
    acc.y = fmaf(a, p.y, acc.y);
    acc.z = fmaf(a, p.z, acc.z);
    acc.w = fmaf(a, p.w, acc.w);
    sa += a;
  }
#pragma unroll
  for (int m = 16; m < 64; m <<= 1) {
    acc.x += __shfl_xor(acc.x, m);
    acc.y += __shfl_xor(acc.y, m);
    acc.z += __shfl_xor(acc.z, m);
    acc.w += __shfl_xor(acc.w, m);
    sa += __shfl_xor(sa, m);
  }
  if (sub == 0) {
    const float4 hb = ((const float4*)hbias)[q];
    float* op = out + (size_t)n * D + q * 4;
    float4 cur = *(float4*)op;      // self-loop already there
    cur.x += acc.x + sa * hb.x;
    cur.y += acc.y + sa * hb.y;
    cur.z += acc.z + sa * hb.z;
    cur.w += acc.w + sa * hb.w;
    *(float4*)op = cur;
  }
}

// ---------------- fallback: atomic scatter ----------------
__global__ __launch_bounds__(256, 8) void edge_scatter(const int* __restrict__ esrc,
                                                       const int* __restrict__ edst,
                                                       const int* __restrict__ etype,
                                                       const float* __restrict__ att,
                                                       const float* __restrict__ proj,
                                                       const float* __restrict__ hbias,
                                                       float* __restrict__ out,
                                                       int E, int N, int relFilter) {
  const int t = blockIdx.x * 256 + threadIdx.x;
  const int wave = t >> 6;
  const int lane = threadIdx.x & 63;
  const int sub = lane >> 4;
  const int q = lane & 15;
  const long e = (long)wave * 4 + sub;
  if (e >= E) return;
  const int r = etype[e];
  if (relFilter >= 0 && r != relFilter) return;
  const int s = esrc[e];
  const int dn = edst[e];
  const float a = att[e];
  const size_t base = (relFilter >= 0) ? (size_t)s * D : ((size_t)r * N + s) * D;
  const float4 hb = ((const float4*)hbias)[q];
  const float4 p = *(const float4*)(proj + base + q * 4);
  float* op = out + (size_t)dn * D + q * 4;
  unsafeAtomicAdd(op + 0, (p.x + hb.x) * a);
  unsafeAtomicAdd(op + 1, (p.y + hb.y) * a);
  unsafeAtomicAdd(op + 2, (p.z + hb.z) * a);
  unsafeAtomicAdd(op + 3, (p.w + hb.w) * a);
}

extern "C" void kernel_launch(void* const* d_in, const int* in_sizes, int n_in,
                              void* d_out, int out_size, void* d_ws, size_t ws_size,
                              hipStream_t stream) {
  const float* feat   = (const float*)d_in[0];
  const int* esrc     = (const int*)d_in[1];
  const int* edst     = (const int*)d_in[2];
  const int* etype    = (const int*)d_in[3];
  const float* att    = (const float*)d_in[4];
  const float* weight = (const float*)d_in[5];
  const float* hbias  = (const float*)d_in[6];
  const float* loopw  = (const float*)d_in[7];
  float* out = (float*)d_out;

  const int N = in_sizes[0] / D;          // 50000
  const int E = in_sizes[1];              // 800000
  const int R = in_sizes[5] / (D * D);    // 8

  const size_t projFloats = (size_t)R * N * D;
  const int Npad = (N + 3) & ~3;          // keep deg 16B-aligned for int4
  const int nb = (N + 1023) / 1024;
  const size_t extraInts = (size_t)Npad + (size_t)(N + 1) + (size_t)N + (size_t)nb
                           + 2 * (size_t)E;
  const size_t needSorted = (projFloats + extraInts) * 4;
  const size_t needAtomic = projFloats * 4;

  float* proj = (float*)d_ws;
  const int tilesN = (N + 127) / 128;
  const int eblocks256 = (E + 255) / 256;

  if (ws_size >= needSorted) {
    int* deg    = (int*)(proj + projFloats);   // Npad ints, 16B-aligned
    int* off    = deg + Npad;                  // N+1
    int* cursor = off + (N + 1);               // N
    int* bsum   = cursor + N;                  // nb (doubles as boff)
    int* ssr    = bsum + nb;                   // E
    float* satt = (float*)(ssr + E);           // E

    proj_all<<<dim3(tilesN, R + 1), 256, 0, stream>>>(feat, weight, loopw, proj, out, N, R);
    zero_ints<<<(N + 255) / 256, 256, 0, stream>>>(deg, N);
    hist_dst<<<eblocks256, 256, 0, stream>>>(edst, deg, E);
    scan_partial<<<nb, 256, 0, stream>>>(deg, bsum, N);
    scan_bsum<<<1, 256, 0, stream>>>(bsum, bsum, off, nb, N);   // in-place: boff == bsum
    scan_apply<<<nb, 256, 0, stream>>>(deg, bsum, off, cursor, N);
    scatter_idx<<<eblocks256, 256, 0, stream>>>(esrc, edst, etype, att, cursor, ssr, satt, E);
    node_gather<<<(N + 3) / 4, 256, 0, stream>>>(off, ssr, satt, proj, hbias, out, N);
  } else if (ws_size >= needAtomic) {
    const int eblocks16 = (E + 15) / 16;
    proj_all<<<dim3(tilesN, R + 1), 256, 0, stream>>>(feat, weight, loopw, proj, out, N, R);
    edge_scatter<<<eblocks16, 256, 0, stream>>>(esrc, edst, etype, att, proj, hbias, out, E, N, -1);
  } else {
    const int eblocks16 = (E + 15) / 16;
    proj_single<<<tilesN, 256, 0, stream>>>(feat, loopw, out, N);
    for (int r = 0; r < R; ++r) {
      proj_single<<<tilesN, 256, 0, stream>>>(feat, weight + (size_t)r * D * D, proj, N);
      edge_scatter<<<eblocks16, 256, 0, stream>>>(esrc, edst, etype, att, proj, hbias, out, E, N, r);
    }
  }
}